// Round 1
// 118.014 us; speedup vs baseline: 1.0594x; 1.0594x over previous
//
#include <hip/hip_runtime.h>
#include <hip/hip_bf16.h>

typedef __attribute__((ext_vector_type(8))) short short8;
typedef __attribute__((ext_vector_type(4))) float floatx4;
typedef __attribute__((ext_vector_type(4))) unsigned int uintx4;
#define BF16 __hip_bfloat16

__device__ __forceinline__ unsigned short f2bf(float f) {
  unsigned int u = __builtin_bit_cast(unsigned int, f);
  unsigned int r = (u + 0x7FFFu + ((u >> 16) & 1u)) >> 16;
  return (unsigned short)r;
}

__device__ __forceinline__ unsigned int cvt_pk_bf16(float lo, float hi) {
  unsigned int r;
  asm("v_cvt_pk_bf16_f32 %0, %1, %2" : "=v"(r) : "v"(lo), "v"(hi));
  return r;
}

__device__ __forceinline__ void gload_lds16(const void* g, void* l) {
  __builtin_amdgcn_global_load_lds(
      (const __attribute__((address_space(1))) unsigned int*)g,
      (__attribute__((address_space(3))) unsigned int*)l, 16, 0, 0);
}

// ---------- elementwise f32 -> bf16 ----------
__global__ __launch_bounds__(256)
void cvt_bf16(const float* __restrict__ in, unsigned short* __restrict__ out, int n) {
  int i = (blockIdx.x * 256 + threadIdx.x) * 8;
  if (i >= n) return;
  float4 a = *(const float4*)(in + i);
  float4 b = *(const float4*)(in + i + 4);
  short8 v;
  v[0] = (short)f2bf(a.x); v[1] = (short)f2bf(a.y);
  v[2] = (short)f2bf(a.z); v[3] = (short)f2bf(a.w);
  v[4] = (short)f2bf(b.x); v[5] = (short)f2bf(b.y);
  v[6] = (short)f2bf(b.z); v[7] = (short)f2bf(b.w);
  *(short8*)(out + i) = v;
}

// ---------- transpose+convert: in[K][N] f32 -> out[N][K] bf16 ----------
__global__ __launch_bounds__(256)
void transpose_cvt(const float* __restrict__ in, unsigned short* __restrict__ out,
                   int K, int N) {
  __shared__ float tile[64][65];
  const int nb = N >> 6;
  const int tn = blockIdx.x % nb, tk = blockIdx.x / nb;
  const int n0 = tn << 6, k0 = tk << 6;
  const int tid = threadIdx.x;
#pragma unroll
  for (int c = 0; c < 4; ++c) {
    int t = tid + c * 256;            // [0,1024): 64 rows x 16 float4
    int r = t >> 4, col = (t & 15) << 2;
    float4 v = *(const float4*)(in + (size_t)(k0 + r) * N + n0 + col);
    tile[r][col] = v.x; tile[r][col + 1] = v.y;
    tile[r][col + 2] = v.z; tile[r][col + 3] = v.w;
  }
  __syncthreads();
#pragma unroll
  for (int c = 0; c < 2; ++c) {
    int t = tid + c * 256;            // [0,512): 64 n-rows x 8 short8
    int r = t >> 3, col = (t & 7) << 3;   // r = local n, col = local k
    short8 v;
#pragma unroll
    for (int j = 0; j < 8; ++j) v[j] = (short)f2bf(tile[col + j][r]);
    *(short8*)(out + (size_t)(n0 + r) * K + k0 + col) = v;
  }
}

// ---------- GEMM: C[M][N] = A[M][K] @ Bt[N][K]^T + bias ----------
// EPI 0: scatter-write qkv bf16 (q,k -> [2][16][2048][64]; v -> [2][16][64][2048])
// EPI 1: plain row-major [M][N] f32 write
template <int EPI>
__global__ __launch_bounds__(256, 2)
void gemm_bt(const BF16* __restrict__ A, const BF16* __restrict__ Bt,
             const float* __restrict__ bias, void* __restrict__ outv,
             int M, int N, int K) {
  const int tid = threadIdx.x;
  const int w = tid >> 6, l = tid & 63;
  const int lr = l & 15, lg = l >> 4;
  const int nbx = N >> 7;
  const int bm = blockIdx.x / nbx, bn = blockIdx.x % nbx;
  const int row0 = bm << 7, col0 = bn << 7;
  const int wr = (w >> 1) << 6, wc = (w & 1) << 6;

  __shared__ __align__(16) BF16 ldsA[128 * 32];
  __shared__ __align__(16) BF16 ldsB[128 * 32];

  floatx4 acc[4][4] = {};

  for (int k0 = 0; k0 < K; k0 += 32) {
#pragma unroll
    for (int c = 0; c < 2; ++c) {
      int t = w * 64 + l + c * 256;
      int ar = t >> 2, ac = (t & 3) << 3;
      gload_lds16(A + (size_t)(row0 + ar) * K + k0 + ac, ldsA + w * 512 + c * 2048);
      gload_lds16(Bt + (size_t)(col0 + ar) * K + k0 + ac, ldsB + w * 512 + c * 2048);
    }
    __syncthreads();
    short8 af[4], bf[4];
#pragma unroll
    for (int m = 0; m < 4; ++m)
      af[m] = *(const short8*)(ldsA + (wr + m * 16 + lr) * 32 + lg * 8);
#pragma unroll
    for (int n = 0; n < 4; ++n)
      bf[n] = *(const short8*)(ldsB + (wc + n * 16 + lr) * 32 + lg * 8);
#pragma unroll
    for (int m = 0; m < 4; ++m)
#pragma unroll
      for (int n = 0; n < 4; ++n)
        acc[m][n] = __builtin_amdgcn_mfma_f32_16x16x32_bf16(af[m], bf[n], acc[m][n], 0, 0, 0);
    __syncthreads();
  }

#pragma unroll
  for (int m = 0; m < 4; ++m)
#pragma unroll
    for (int n = 0; n < 4; ++n)
#pragma unroll
      for (int j = 0; j < 4; ++j) {
        int row = row0 + wr + m * 16 + lg * 4 + j;   // m index (b*2048 + t)
        int col = col0 + wc + n * 16 + lr;           // n index
        float v = acc[m][n][j] + bias[col];
        if (EPI == 0) {
          BF16* out = (BF16*)outv;
          int s = col >> 10, cc = col & 1023;
          int hh = cc >> 6, dd = cc & 63;
          int bb = row >> 11, tt = row & 2047;
          size_t addr;
          if (s == 2)
            addr = (size_t)8388608 + (((size_t)bb * 16 + hh) * 64 + dd) * 2048 + tt;
          else
            addr = (size_t)s * 4194304 + (((size_t)bb * 16 + hh) * 2048 + tt) * 64 + dd;
          out[addr] = __float2bfloat16(v);
        } else {
          float* out = (float*)outv;
          out[(size_t)row * N + col] = v;
        }
      }
}

// ---------- causal flash attention ----------
// q: [2][16][2048][64], k: [2][16][2048][64], vt: [2][16][64][2048]
// y: [2][2048][1024] bf16  (= [B][T][H*D])
// Changes this round:
//  * Balanced long/short q-tile pairing: any 4 consecutive (or stride-32)
//    blocks on a CU sum to ~66 KV tiles (was: up to 4x32=128 under
//    depth-first dispatch -> critical-CU bound, Occupancy 27%).
//  * In-register P (swapped QK^T + v_cvt_pk_bf16_f32 + permlane16/32_swap):
//    removes ldsP entirely (16 ds_write + 16 cvt + 2 ds_read per wave-tile).
//  * ldsV padded so LDS stays 40960 B -> exactly 4 blocks/CU preserved.
__global__ __launch_bounds__(256, 4)
void flash_attn(const BF16* __restrict__ qkv, BF16* __restrict__ y) {
  const int T = 2048;
  const int i = blockIdx.x;
  const int xcd = i & 7, s = i >> 3;          // blocks round-robin XCDs
  // parity alternates under both consecutive (s&1) and stride-32 ((s>>5)&1)
  const int par = (s ^ (s >> 5)) & 1;
  const int rnk = ((s >> 5) << 4) | ((s & 31) >> 1);   // [0,64)
  const int bh = xcd * 4 + (rnk & 3);         // 4 heads per XCD -> 2MB L2 set
  const int hq = rnk >> 2;                    // [0,16)
  const int qt = par ? hq : (31 - hq);        // pair (31-h, h): 33 tiles/pair
  const int b = bh >> 4, h = bh & 15;
  const int q0 = qt << 6;
  const int tid = threadIdx.x, w = tid >> 6, l = tid & 63;
  const int lr = l & 15, lg = l >> 4;

  const BF16* Q  = qkv + (size_t)bh * T * 64;
  const BF16* Kp = qkv + 4194304 + (size_t)bh * T * 64;
  const BF16* Vt = qkv + 8388608 + (size_t)bh * 64 * T;

  __shared__ __align__(16) BF16 ldsK[2][4096];
  __shared__ __align__(16) BF16 ldsV[2][6144];   // padded: LDS stays 40960 B

  const float C1 = 0.18033688011112042f;   // log2(e)/8
  const float C2 = 17.312340490667562f;    // 12*log2(e)  (static max M=12)
  const int swzl = (lr & 7) << 3;          // read-side XOR (elements)
  const int nt = qt + 1;

  // Q fragments for this wave's 16 rows (global, no LDS)
  short8 qf[2];
#pragma unroll
  for (int c = 0; c < 2; ++c)
    qf[c] = *(const short8*)(Q + (size_t)(q0 + w * 16 + lr) * 64 + c * 32 + lg * 8);

  floatx4 acc_o[4] = {};
  float lsum = 0.f;

  // swizzled staging: LDS linear dest, pre-swizzled global source (chunk^row&7)
#define STAGE(JT, BUF)                                                        \
  {                                                                           \
    const int j0_ = (JT) << 6;                                                \
    _Pragma("unroll")                                                         \
    for (int c = 0; c < 2; ++c) {                                             \
      int t = w * 64 + l + c * 256;                                           \
      int r = t >> 3;                                                         \
      int ch = (t & 7) ^ (r & 7);                                             \
      gload_lds16(Kp + (size_t)(j0_ + r) * 64 + ch * 8,                       \
                  &ldsK[BUF][w * 512 + c * 2048]);                            \
      gload_lds16(Vt + (size_t)r * T + j0_ + ch * 8,                          \
                  &ldsV[BUF][w * 512 + c * 2048]);                            \
    }                                                                         \
  }

  STAGE(0, 0);

  for (int jt = 0; jt < nt; ++jt) {
    const int j0 = jt << 6;
    const int cur = jt & 1;
    if (jt + 1 < nt) {
      STAGE(jt + 1, cur ^ 1);
      asm volatile("s_waitcnt vmcnt(4)" ::: "memory");   // tile jt done; jt+1 in flight
    } else {
      asm volatile("s_waitcnt vmcnt(0)" ::: "memory");
    }
    __builtin_amdgcn_s_barrier();

    // S^T = K @ Q^T (swapped): lane holds S[q = q0+w*16+lr][key = j0+n*16+lg*4+j]
    floatx4 accs[4] = {};
    __builtin_amdgcn_s_setprio(1);
#pragma unroll
    for (int c = 0; c < 2; ++c)
#pragma unroll
      for (int n = 0; n < 4; ++n) {
        short8 kf = *(const short8*)(&ldsK[cur][(n * 16 + lr) * 64 + ((c * 32 + lg * 8) ^ swzl)]);
        accs[n] = __builtin_amdgcn_mfma_f32_16x16x32_bf16(kf, qf[c], accs[n], 0, 0, 0);
      }
    __builtin_amdgcn_s_setprio(0);

    // static-max softmax in-register: p = 2^(s*log2e/8 - 12*log2e)
    const bool diag = (jt == qt);
    const int qrow = q0 + w * 16 + lr;
#pragma unroll
    for (int n = 0; n < 4; ++n)
#pragma unroll
      for (int j = 0; j < 4; ++j) {
        float p = exp2f(fmaf(accs[n][j], C1, -C2));
        if (diag && (j0 + n * 16 + lg * 4 + j > qrow)) p = 0.f;
        lsum += p;
        accs[n][j] = p;
      }

    // O += P @ V ; P-fragments built in-register:
    // cvt_pk pairs keys {2g,2g+1}; permlane32_swap gathers n-halves across the
    // 32-lane split; permlane16_swap exchanges lg0<->lg1 / lg2<->lg3.
    // Result: pf[c] = P[q=lr][keys c*32+lg*8+0..7]  (exact PV A-fragment).
    __builtin_amdgcn_s_setprio(1);
#pragma unroll
    for (int c = 0; c < 2; ++c) {
      unsigned int a0 = cvt_pk_bf16(accs[2 * c][0], accs[2 * c][1]);
      unsigned int b0 = cvt_pk_bf16(accs[2 * c + 1][0], accs[2 * c + 1][1]);
      unsigned int a1 = cvt_pk_bf16(accs[2 * c][2], accs[2 * c][3]);
      unsigned int b1 = cvt_pk_bf16(accs[2 * c + 1][2], accs[2 * c + 1][3]);
      asm("v_permlane32_swap_b32 %0, %1" : "+v"(a0), "+v"(b0));
      asm("v_permlane32_swap_b32 %0, %1" : "+v"(a1), "+v"(b1));
      asm("v_permlane16_swap_b32 %0, %1" : "+v"(a0), "+v"(b0));
      asm("v_permlane16_swap_b32 %0, %1" : "+v"(a1), "+v"(b1));
      uintx4 pw;
      pw[0] = a0; pw[1] = a1; pw[2] = b0; pw[3] = b1;
      short8 pf = __builtin_bit_cast(short8, pw);
#pragma unroll
      for (int n = 0; n < 4; ++n) {
        short8 vf = *(const short8*)(&ldsV[cur][(n * 16 + lr) * 64 + ((c * 32 + lg * 8) ^ swzl)]);
        acc_o[n] = __builtin_amdgcn_mfma_f32_16x16x32_bf16(pf, vf, acc_o[n], 0, 0, 0);
      }
    }
    __builtin_amdgcn_s_setprio(0);
    __builtin_amdgcn_s_barrier();   // buf[cur] free for iter jt+1's prefetch target jt+2
  }
#undef STAGE

  // row-sum lives split across the 4 lg-groups of each q-row (lr): reduce over
  // lanes +-16/+-32, then broadcast the inv for output rows lg*4+j from lanes 0-15.
  lsum += __shfl_xor(lsum, 16, 64);
  lsum += __shfl_xor(lsum, 32, 64);
  float inv_own = 1.0f / lsum;
  float inv[4];
#pragma unroll
  for (int j = 0; j < 4; ++j) inv[j] = __shfl(inv_own, lg * 4 + j, 64);
#pragma unroll
  for (int n = 0; n < 4; ++n)
#pragma unroll
    for (int j = 0; j < 4; ++j) {
      int qr = q0 + w * 16 + lg * 4 + j;
      int dd = n * 16 + lr;
      y[((size_t)b * 2048 + qr) * 1024 + h * 64 + dd] =
          __float2bfloat16(acc_o[n][j] * inv[j]);
    }
}

extern "C" void kernel_launch(void* const* d_in, const int* in_sizes, int n_in,
                              void* d_out, int out_size, void* d_ws, size_t ws_size,
                              hipStream_t stream) {
  const float* x      = (const float*)d_in[0];
  const float* W_attn = (const float*)d_in[1];
  const float* b_attn = (const float*)d_in[2];
  const float* W_proj = (const float*)d_in[3];
  const float* b_proj = (const float*)d_in[4];
  float* out = (float*)d_out;
  BF16* ws  = (BF16*)d_ws;

  BF16* xb      = ws;                               // [4096][1024]
  BF16* wt_attn = xb + 4194304;                     // [3072][1024]
  BF16* wt_proj = wt_attn + 3145728;                // [1024][1024]
  BF16* qkv     = wt_proj + 1048576;                // q,k,vt (12582912 elems)
  BF16* y       = qkv + 12582912;                   // [4096][1024]

  hipLaunchKernelGGL(cvt_bf16, dim3(2048), dim3(256), 0, stream,
                     x, (unsigned short*)xb, 4194304);
  hipLaunchKernelGGL(transpose_cvt, dim3(48 * 16), dim3(256), 0, stream,
                     W_attn, (unsigned short*)wt_attn, 1024, 3072);
  hipLaunchKernelGGL(transpose_cvt, dim3(16 * 16), dim3(256), 0, stream,
                     W_proj, (unsigned short*)wt_proj, 1024, 1024);
  hipLaunchKernelGGL(gemm_bt<0>, dim3(32 * 24), dim3(256), 0, stream,
                     xb, wt_attn, b_attn, (void*)qkv, 4096, 3072, 1024);
  hipLaunchKernelGGL(flash_attn, dim3(1024), dim3(256), 0, stream, qkv, y);
  hipLaunchKernelGGL(gemm_bt<1>, dim3(32 * 8), dim3(256), 0, stream,
                     y, wt_proj, b_proj, (void*)out, 4096, 1024, 1024);
}

// Round 2
// 109.907 us; speedup vs baseline: 1.1375x; 1.0738x over previous
//
#include <hip/hip_runtime.h>
#include <hip/hip_bf16.h>

typedef __attribute__((ext_vector_type(8))) short short8;
typedef __attribute__((ext_vector_type(4))) float floatx4;
typedef __attribute__((ext_vector_type(4))) unsigned int uintx4;
#define BF16 __hip_bfloat16

__device__ __forceinline__ unsigned short f2bf(float f) {
  unsigned int u = __builtin_bit_cast(unsigned int, f);
  unsigned int r = (u + 0x7FFFu + ((u >> 16) & 1u)) >> 16;
  return (unsigned short)r;
}

__device__ __forceinline__ unsigned int cvt_pk_bf16(float lo, float hi) {
  unsigned int r;
  asm("v_cvt_pk_bf16_f32 %0, %1, %2" : "=v"(r) : "v"(lo), "v"(hi));
  return r;
}

__device__ __forceinline__ void gload_lds16(const void* g, void* l) {
  __builtin_amdgcn_global_load_lds(
      (const __attribute__((address_space(1))) unsigned int*)g,
      (__attribute__((address_space(3))) unsigned int*)l, 16, 0, 0);
}

// ---------- elementwise f32 -> bf16 ----------
__global__ __launch_bounds__(256)
void cvt_bf16(const float* __restrict__ in, unsigned short* __restrict__ out, int n) {
  int i = (blockIdx.x * 256 + threadIdx.x) * 8;
  if (i >= n) return;
  float4 a = *(const float4*)(in + i);
  float4 b = *(const float4*)(in + i + 4);
  short8 v;
  v[0] = (short)f2bf(a.x); v[1] = (short)f2bf(a.y);
  v[2] = (short)f2bf(a.z); v[3] = (short)f2bf(a.w);
  v[4] = (short)f2bf(b.x); v[5] = (short)f2bf(b.y);
  v[6] = (short)f2bf(b.z); v[7] = (short)f2bf(b.w);
  *(short8*)(out + i) = v;
}

// ---------- transpose+convert: in[K][N] f32 -> out[N][K] bf16 ----------
__global__ __launch_bounds__(256)
void transpose_cvt(const float* __restrict__ in, unsigned short* __restrict__ out,
                   int K, int N) {
  __shared__ float tile[64][65];
  const int nb = N >> 6;
  const int tn = blockIdx.x % nb, tk = blockIdx.x / nb;
  const int n0 = tn << 6, k0 = tk << 6;
  const int tid = threadIdx.x;
#pragma unroll
  for (int c = 0; c < 4; ++c) {
    int t = tid + c * 256;            // [0,1024): 64 rows x 16 float4
    int r = t >> 4, col = (t & 15) << 2;
    float4 v = *(const float4*)(in + (size_t)(k0 + r) * N + n0 + col);
    tile[r][col] = v.x; tile[r][col + 1] = v.y;
    tile[r][col + 2] = v.z; tile[r][col + 3] = v.w;
  }
  __syncthreads();
#pragma unroll
  for (int c = 0; c < 2; ++c) {
    int t = tid + c * 256;            // [0,512): 64 n-rows x 8 short8
    int r = t >> 3, col = (t & 7) << 3;   // r = local n, col = local k
    short8 v;
#pragma unroll
    for (int j = 0; j < 8; ++j) v[j] = (short)f2bf(tile[col + j][r]);
    *(short8*)(out + (size_t)(n0 + r) * K + k0 + col) = v;
  }
}

// ---------- GEMM: C[M][N] = A[M][K] @ Bt[N][K]^T + bias ----------
// BK=64 (was 32): 32 MFMA per barrier-pair instead of 16 -> halves the
// per-K-step stage+vmcnt(0)+barrier stall (m233: ~72% of 2-phase time).
// LDS 32KB/block, 3 blocks/CU (grid-limited anyway).
// Tiles are XOR-swizzled both-sides (pre-swizzled global source chunk,
// read-side element XOR) so the [128][64] row-major fragment reads are
// 2-way (free) instead of 16-way bank conflicts.
// EPI 0: scatter-write qkv bf16 (q,k -> [2][16][2048][64]; v -> [2][16][64][2048])
// EPI 1: plain row-major [M][N] f32 write
template <int EPI>
__global__ __launch_bounds__(256, 2)
void gemm_bt(const BF16* __restrict__ A, const BF16* __restrict__ Bt,
             const float* __restrict__ bias, void* __restrict__ outv,
             int M, int N, int K) {
  const int tid = threadIdx.x;
  const int w = tid >> 6, l = tid & 63;
  const int lr = l & 15, lg = l >> 4;
  const int nbx = N >> 7;
  const int bm = blockIdx.x / nbx, bn = blockIdx.x % nbx;
  const int row0 = bm << 7, col0 = bn << 7;
  const int wr = (w >> 1) << 6, wc = (w & 1) << 6;

  __shared__ __align__(16) BF16 ldsA[128 * 64];
  __shared__ __align__(16) BF16 ldsB[128 * 64];

  floatx4 acc[4][4] = {};
  const int swzl = (lr & 7) << 3;   // read-side XOR (elements); row&7 == lr&7

  for (int k0 = 0; k0 < K; k0 += 64) {
#pragma unroll
    for (int c = 0; c < 4; ++c) {
      int t = w * 64 + l + c * 256;        // [0,1024): 128 rows x 8 chunks(16B)
      int ar = t >> 3;
      int ch = (t & 7) ^ (ar & 7);         // pre-swizzled source chunk
      gload_lds16(A + (size_t)(row0 + ar) * K + k0 + (ch << 3),
                  ldsA + w * 512 + c * 2048);
      gload_lds16(Bt + (size_t)(col0 + ar) * K + k0 + (ch << 3),
                  ldsB + w * 512 + c * 2048);
    }
    __syncthreads();
#pragma unroll
    for (int kk = 0; kk < 64; kk += 32) {
      short8 af[4], bf[4];
#pragma unroll
      for (int m = 0; m < 4; ++m)
        af[m] = *(const short8*)(ldsA + (wr + m * 16 + lr) * 64 + ((kk + lg * 8) ^ swzl));
#pragma unroll
      for (int n = 0; n < 4; ++n)
        bf[n] = *(const short8*)(ldsB + (wc + n * 16 + lr) * 64 + ((kk + lg * 8) ^ swzl));
#pragma unroll
      for (int m = 0; m < 4; ++m)
#pragma unroll
        for (int n = 0; n < 4; ++n)
          acc[m][n] = __builtin_amdgcn_mfma_f32_16x16x32_bf16(af[m], bf[n], acc[m][n], 0, 0, 0);
    }
    __syncthreads();
  }

#pragma unroll
  for (int m = 0; m < 4; ++m)
#pragma unroll
    for (int n = 0; n < 4; ++n)
#pragma unroll
      for (int j = 0; j < 4; ++j) {
        int row = row0 + wr + m * 16 + lg * 4 + j;   // m index (b*2048 + t)
        int col = col0 + wc + n * 16 + lr;           // n index
        float v = acc[m][n][j] + bias[col];
        if (EPI == 0) {
          BF16* out = (BF16*)outv;
          int s = col >> 10, cc = col & 1023;
          int hh = cc >> 6, dd = cc & 63;
          int bb = row >> 11, tt = row & 2047;
          size_t addr;
          if (s == 2)
            addr = (size_t)8388608 + (((size_t)bb * 16 + hh) * 64 + dd) * 2048 + tt;
          else
            addr = (size_t)s * 4194304 + (((size_t)bb * 16 + hh) * 2048 + tt) * 64 + dd;
          out[addr] = __float2bfloat16(v);
        } else {
          float* out = (float*)outv;
          out[(size_t)row * N + col] = v;
        }
      }
}

// ---------- causal flash attention ----------
// q: [2][16][2048][64], k: [2][16][2048][64], vt: [2][16][64][2048]
// y: [2][2048][1024] bf16  (= [B][T][H*D])
//  * Balanced long/short q-tile pairing (consecutive-4 and stride-32 safe).
//  * In-register P (swapped QK^T + v_cvt_pk_bf16_f32 + permlane16/32_swap).
//  * ldsV padded so LDS stays 40960 B -> exactly 4 blocks/CU preserved.
__global__ __launch_bounds__(256, 4)
void flash_attn(const BF16* __restrict__ qkv, BF16* __restrict__ y) {
  const int T = 2048;
  const int i = blockIdx.x;
  const int xcd = i & 7, s = i >> 3;          // blocks round-robin XCDs
  // parity alternates under both consecutive (s&1) and stride-32 ((s>>5)&1)
  const int par = (s ^ (s >> 5)) & 1;
  const int rnk = ((s >> 5) << 4) | ((s & 31) >> 1);   // [0,64)
  const int bh = xcd * 4 + (rnk & 3);         // 4 heads per XCD -> 2MB L2 set
  const int hq = rnk >> 2;                    // [0,16)
  const int qt = par ? hq : (31 - hq);        // pair (31-h, h): 33 tiles/pair
  const int b = bh >> 4, h = bh & 15;
  const int q0 = qt << 6;
  const int tid = threadIdx.x, w = tid >> 6, l = tid & 63;
  const int lr = l & 15, lg = l >> 4;

  const BF16* Q  = qkv + (size_t)bh * T * 64;
  const BF16* Kp = qkv + 4194304 + (size_t)bh * T * 64;
  const BF16* Vt = qkv + 8388608 + (size_t)bh * 64 * T;

  __shared__ __align__(16) BF16 ldsK[2][4096];
  __shared__ __align__(16) BF16 ldsV[2][6144];   // padded: LDS stays 40960 B

  const float C1 = 0.18033688011112042f;   // log2(e)/8
  const float C2 = 17.312340490667562f;    // 12*log2(e)  (static max M=12)
  const int swzl = (lr & 7) << 3;          // read-side XOR (elements)
  const int nt = qt + 1;

  // Q fragments for this wave's 16 rows (global, no LDS)
  short8 qf[2];
#pragma unroll
  for (int c = 0; c < 2; ++c)
    qf[c] = *(const short8*)(Q + (size_t)(q0 + w * 16 + lr) * 64 + c * 32 + lg * 8);

  floatx4 acc_o[4] = {};
  float lsum = 0.f;

  // swizzled staging: LDS linear dest, pre-swizzled global source (chunk^row&7)
#define STAGE(JT, BUF)                                                        \
  {                                                                           \
    const int j0_ = (JT) << 6;                                                \
    _Pragma("unroll")                                                         \
    for (int c = 0; c < 2; ++c) {                                             \
      int t = w * 64 + l + c * 256;                                           \
      int r = t >> 3;                                                         \
      int ch = (t & 7) ^ (r & 7);                                             \
      gload_lds16(Kp + (size_t)(j0_ + r) * 64 + ch * 8,                       \
                  &ldsK[BUF][w * 512 + c * 2048]);                            \
      gload_lds16(Vt + (size_t)r * T + j0_ + ch * 8,                          \
                  &ldsV[BUF][w * 512 + c * 2048]);                            \
    }                                                                         \
  }

  STAGE(0, 0);

  for (int jt = 0; jt < nt; ++jt) {
    const int j0 = jt << 6;
    const int cur = jt & 1;
    if (jt + 1 < nt) {
      STAGE(jt + 1, cur ^ 1);
      asm volatile("s_waitcnt vmcnt(4)" ::: "memory");   // tile jt done; jt+1 in flight
    } else {
      asm volatile("s_waitcnt vmcnt(0)" ::: "memory");
    }
    __builtin_amdgcn_s_barrier();

    // S^T = K @ Q^T (swapped): lane holds S[q = q0+w*16+lr][key = j0+n*16+lg*4+j]
    floatx4 accs[4] = {};
    __builtin_amdgcn_s_setprio(1);
#pragma unroll
    for (int c = 0; c < 2; ++c)
#pragma unroll
      for (int n = 0; n < 4; ++n) {
        short8 kf = *(const short8*)(&ldsK[cur][(n * 16 + lr) * 64 + ((c * 32 + lg * 8) ^ swzl)]);
        accs[n] = __builtin_amdgcn_mfma_f32_16x16x32_bf16(kf, qf[c], accs[n], 0, 0, 0);
      }
    __builtin_amdgcn_s_setprio(0);

    // static-max softmax in-register: p = 2^(s*log2e/8 - 12*log2e)
    const bool diag = (jt == qt);
    const int qrow = q0 + w * 16 + lr;
#pragma unroll
    for (int n = 0; n < 4; ++n)
#pragma unroll
      for (int j = 0; j < 4; ++j) {
        float p = exp2f(fmaf(accs[n][j], C1, -C2));
        if (diag && (j0 + n * 16 + lg * 4 + j > qrow)) p = 0.f;
        lsum += p;
        accs[n][j] = p;
      }

    // O += P @ V ; P-fragments built in-register:
    // cvt_pk pairs keys {2g,2g+1}; permlane32_swap gathers n-halves across the
    // 32-lane split; permlane16_swap exchanges lg0<->lg1 / lg2<->lg3.
    // Result: pf[c] = P[q=lr][keys c*32+lg*8+0..7]  (exact PV A-fragment).
    __builtin_amdgcn_s_setprio(1);
#pragma unroll
    for (int c = 0; c < 2; ++c) {
      unsigned int a0 = cvt_pk_bf16(accs[2 * c][0], accs[2 * c][1]);
      unsigned int b0 = cvt_pk_bf16(accs[2 * c + 1][0], accs[2 * c + 1][1]);
      unsigned int a1 = cvt_pk_bf16(accs[2 * c][2], accs[2 * c][3]);
      unsigned int b1 = cvt_pk_bf16(accs[2 * c + 1][2], accs[2 * c + 1][3]);
      asm("v_permlane32_swap_b32 %0, %1" : "+v"(a0), "+v"(b0));
      asm("v_permlane32_swap_b32 %0, %1" : "+v"(a1), "+v"(b1));
      asm("v_permlane16_swap_b32 %0, %1" : "+v"(a0), "+v"(b0));
      asm("v_permlane16_swap_b32 %0, %1" : "+v"(a1), "+v"(b1));
      uintx4 pw;
      pw[0] = a0; pw[1] = a1; pw[2] = b0; pw[3] = b1;
      short8 pf = __builtin_bit_cast(short8, pw);
#pragma unroll
      for (int n = 0; n < 4; ++n) {
        short8 vf = *(const short8*)(&ldsV[cur][(n * 16 + lr) * 64 + ((c * 32 + lg * 8) ^ swzl)]);
        acc_o[n] = __builtin_amdgcn_mfma_f32_16x16x32_bf16(pf, vf, acc_o[n], 0, 0, 0);
      }
    }
    __builtin_amdgcn_s_setprio(0);
    __builtin_amdgcn_s_barrier();   // buf[cur] free for iter jt+1's prefetch target jt+2
  }
#undef STAGE

  // row-sum lives split across the 4 lg-groups of each q-row (lr): reduce over
  // lanes +-16/+-32, then broadcast the inv for output rows lg*4+j from lanes 0-15.
  lsum += __shfl_xor(lsum, 16, 64);
  lsum += __shfl_xor(lsum, 32, 64);
  float inv_own = 1.0f / lsum;
  float inv[4];
#pragma unroll
  for (int j = 0; j < 4; ++j) inv[j] = __shfl(inv_own, lg * 4 + j, 64);
#pragma unroll
  for (int n = 0; n < 4; ++n)
#pragma unroll
    for (int j = 0; j < 4; ++j) {
      int qr = q0 + w * 16 + lg * 4 + j;
      int dd = n * 16 + lr;
      y[((size_t)b * 2048 + qr) * 1024 + h * 64 + dd] =
          __float2bfloat16(acc_o[n][j] * inv[j]);
    }
}

extern "C" void kernel_launch(void* const* d_in, const int* in_sizes, int n_in,
                              void* d_out, int out_size, void* d_ws, size_t ws_size,
                              hipStream_t stream) {
  const float* x      = (const float*)d_in[0];
  const float* W_attn = (const float*)d_in[1];
  const float* b_attn = (const float*)d_in[2];
  const float* W_proj = (const float*)d_in[3];
  const float* b_proj = (const float*)d_in[4];
  float* out = (float*)d_out;
  BF16* ws  = (BF16*)d_ws;

  BF16* xb      = ws;                               // [4096][1024]
  BF16* wt_attn = xb + 4194304;                     // [3072][1024]
  BF16* wt_proj = wt_attn + 3145728;                // [1024][1024]
  BF16* qkv     = wt_proj + 1048576;                // q,k,vt (12582912 elems)
  BF16* y       = qkv + 12582912;                   // [4096][1024]

  hipLaunchKernelGGL(cvt_bf16, dim3(2048), dim3(256), 0, stream,
                     x, (unsigned short*)xb, 4194304);
  hipLaunchKernelGGL(transpose_cvt, dim3(48 * 16), dim3(256), 0, stream,
                     W_attn, (unsigned short*)wt_attn, 1024, 3072);
  hipLaunchKernelGGL(transpose_cvt, dim3(16 * 16), dim3(256), 0, stream,
                     W_proj, (unsigned short*)wt_proj, 1024, 1024);
  hipLaunchKernelGGL(gemm_bt<0>, dim3(32 * 24), dim3(256), 0, stream,
                     xb, wt_attn, b_attn, (void*)qkv, 4096, 3072, 1024);
  hipLaunchKernelGGL(flash_attn, dim3(1024), dim3(256), 0, stream, qkv, y);
  hipLaunchKernelGGL(gemm_bt<1>, dim3(32 * 8), dim3(256), 0, stream,
                     y, wt_proj, b_proj, (void*)out, 4096, 1024, 1024);
}